// Round 18
// baseline (124.669 us; speedup 1.0000x reference)
//
#include <hip/hip_runtime.h>
#include <hip/hip_bf16.h>
#include <stdint.h>

// B=2, S=2048, D=1024, H=16, HD=64.
// KL bias = per-row constant -> softmax-invariant -> dropped.
// out = softmax(QK^T/8) V with 4 dense projections. bf16 MFMA, fp32 accum.
// Q pre-scaled by log2(e)/8 so softmax is exp2().
// Round 18: r17 (111.4us best) + XCD-chunked block swizzle on both GEMMs
// (T1): blocks sharing a B panel land on one XCD -> B fill is L2-local
// instead of 8x-replicated across XCDs.

#define NB 2
#define NS 2048
#define ND 1024
#define NH 16
#define HD 64

typedef short bf16x8 __attribute__((ext_vector_type(8)));
typedef short bf16x4 __attribute__((ext_vector_type(4)));
typedef float f32x4 __attribute__((ext_vector_type(4)));
typedef float f32x16 __attribute__((ext_vector_type(16)));
typedef unsigned int u32x4 __attribute__((ext_vector_type(4)));

static __device__ __forceinline__ short f2bf(float f) {
    uint32_t u = __builtin_bit_cast(uint32_t, f);
    uint32_t r = (u + 0x7fffu + ((u >> 16) & 1u)) >> 16;
    return (short)(uint16_t)r;
}

static __device__ __forceinline__ unsigned int cvtpk(float lo, float hi) {
    unsigned int r;
    asm("v_cvt_pk_bf16_f32 %0, %1, %2" : "=v"(r) : "v"(lo), "v"(hi));
    return r;
}

#if __has_builtin(__builtin_amdgcn_exp2f)
#define EXP2(x) __builtin_amdgcn_exp2f(x)
#else
#define EXP2(x) exp2f(x)
#endif

static __device__ __forceinline__ void plswap(unsigned& a, unsigned& b) {
#if __has_builtin(__builtin_amdgcn_permlane32_swap)
    auto r = __builtin_amdgcn_permlane32_swap(a, b, false, false);
    a = r[0]; b = r[1];
#else
    const int l = (int)(threadIdx.x & 63);
    unsigned bl = __shfl(b, l & 31);
    unsigned ah = __shfl(a, (l & 31) + 32);
    a = (l < 32) ? a : bl;
    b = (l < 32) ? ah : b;
#endif
}

typedef __attribute__((address_space(1))) const unsigned int glob_u32;
typedef __attribute__((address_space(3))) unsigned int lds_u32;
static __device__ __forceinline__ void gload16(const void* g, void* l) {
    __builtin_amdgcn_global_load_lds((glob_u32*)g, (lds_u32*)l, 16, 0, 0);
}

#define VMW(N) do { asm volatile("s_waitcnt vmcnt(" #N ")" ::: "memory"); \
                    __builtin_amdgcn_sched_barrier(0); } while (0)
#define BAR()  do { __builtin_amdgcn_s_barrier();                          \
                    __builtin_amdgcn_sched_barrier(0); } while (0)
#define SFENCE() __builtin_amdgcn_sched_barrier(0)

// ---------------------------------------------------------------------------
// prep_all: z=0..2 -> fp32->bf16 cast of query/key/value (2048 blocks each);
//           z=3    -> Wt[n][k] = bf16(W[k][n]) for 4 weights (2 tiles/block).
// ---------------------------------------------------------------------------
__global__ __launch_bounds__(256) void prep_all(const float* __restrict__ q,
                                                const float* __restrict__ k,
                                                const float* __restrict__ v,
                                                const float* __restrict__ W0,
                                                const float* __restrict__ W1,
                                                const float* __restrict__ W2,
                                                const float* __restrict__ W3,
                                                short* __restrict__ Qo,
                                                short* __restrict__ Ko,
                                                short* __restrict__ Vo,
                                                short* __restrict__ WtAll) {
    __shared__ short tile[32][33];
    const int z = blockIdx.z;
    if (z < 3) {
        const float* src = (z == 0) ? q : (z == 1) ? k : v;
        short* dst = (z == 0) ? Qo : (z == 1) ? Ko : Vo;
        const size_t i = ((size_t)blockIdx.x * 256 + threadIdx.x) * 8;
        f32x4 a = *(const f32x4*)(src + i);
        f32x4 b = *(const f32x4*)(src + i + 4);
        bf16x8 o;
        o[0] = f2bf(a[0]); o[1] = f2bf(a[1]); o[2] = f2bf(a[2]); o[3] = f2bf(a[3]);
        o[4] = f2bf(b[0]); o[5] = f2bf(b[1]); o[6] = f2bf(b[2]); o[7] = f2bf(b[3]);
        *(bf16x8*)(dst + i) = o;
        return;
    }
    const int tx = threadIdx.x & 31;
    const int ty = threadIdx.x >> 5;
#pragma unroll 1
    for (int it = 0; it < 2; ++it) {
        const int tt = blockIdx.x * 2 + it;          // 0..4095
        const int which = tt >> 10;
        const float* W = (which == 0) ? W0 : (which == 1) ? W1
                       : (which == 2) ? W2 : W3;
        short* Wt = WtAll + (size_t)which * (ND * ND);
        const int t = tt & 1023;
        const int k0 = (t >> 5) * 32, n0 = (t & 31) * 32;
#pragma unroll
        for (int i = 0; i < 4; i++)
            tile[ty + i * 8][tx] = f2bf(W[(size_t)(k0 + ty + i * 8) * ND + n0 + tx]);
        __syncthreads();
#pragma unroll
        for (int i = 0; i < 4; i++)
            Wt[(size_t)(n0 + ty + i * 8) * ND + k0 + tx] = tile[tx][ty + i * 8];
        __syncthreads();
    }
}

#define QSCALE 0.18033688011112042f  // log2(e)/8

// ---------------------------------------------------------------------------
// GEMM body: 128x128 tile, BK=32, global_load_lds, 3-ring, depth-1 prefetch,
// counted vmcnt, ONE barrier per K-step (safe: 3 does not divide 1+1).
// Both-sides XOR swizzle f(row)=((row^row>>2)&3)<<4.
// gm/gn passed in (caller applies XCD-chunked block swizzle).
// ---------------------------------------------------------------------------
static __device__ __forceinline__ void gemm_stage(const char* A, const char* W,
                                                  char* As3, char* Bs3,
                                                  int buf, int tile,
                                                  int gm, int gn, int lin) {
#pragma unroll
    for (int j = 0; j < 2; j++) {
        const int lj = lin + (j << 10);
        const int row = lj >> 6;
        const int colL = (lj & 63) ^ (((row ^ (row >> 2)) & 3) << 4);
        gload16(A + (size_t)(gm + row) * (ND * 2) + tile * 64 + colL,
                As3 + buf * 8192 + lj);
        gload16(W + (size_t)(gn + row) * (ND * 2) + tile * 64 + colL,
                Bs3 + buf * 8192 + lj);
    }
    SFENCE();
}

static __device__ __forceinline__ void gemm_step(const char* AsB, const char* BsB,
                                                 int wr, int wc, int r, int g,
                                                 f32x4 (&acc)[4][4]) {
    bf16x8 af[4], bfv[4];
#pragma unroll
    for (int m = 0; m < 4; m++) {
        const int ar = wr * 64 + m * 16 + r;
        const int fa = ((ar ^ (ar >> 2)) & 3) << 4;
        af[m] = *(const bf16x8*)(AsB + ar * 64 + ((g << 4) ^ fa));
    }
#pragma unroll
    for (int n = 0; n < 4; n++) {
        const int br = wc * 64 + n * 16 + r;
        const int fb = ((br ^ (br >> 2)) & 3) << 4;
        bfv[n] = *(const bf16x8*)(BsB + br * 64 + ((g << 4) ^ fb));
    }
#pragma unroll
    for (int m = 0; m < 4; m++)
#pragma unroll
        for (int n = 0; n < 4; n++)
            acc[m][n] = __builtin_amdgcn_mfma_f32_16x16x32_bf16(
                af[m], bfv[n], acc[m][n], 0, 0, 0);
}

static __device__ __forceinline__ void gemm_body(const short* __restrict__ A,
                                                 const short* __restrict__ Wt,
                                                 const float* __restrict__ bias,
                                                 void* __restrict__ Out,
                                                 int mode, float scale,
                                                 int gm, int gn,
                                                 char* As3, char* Bs3) {
    const int tid = threadIdx.x;
    const int w = tid >> 6;
    const int l = tid & 63;
    const int r = l & 15;
    const int g = l >> 4;
    const int wr = w >> 1, wc = w & 1;
    const char* Ap = (const char*)A;
    const char* Wp = (const char*)Wt;

    f32x4 acc[4][4];
#pragma unroll
    for (int m = 0; m < 4; m++)
#pragma unroll
        for (int n = 0; n < 4; n++) acc[m][n] = (f32x4){0.f, 0.f, 0.f, 0.f};

    const int lin = ((w * 2) << 10) + l * 16;

    // prologue: tile 0 -> buf 0
    gemm_stage(Ap, Wp, As3, Bs3, 0, 0, gm, gn, lin);

    int cur = 0;
#pragma unroll 1
    for (int t = 0; t < ND / 32 - 1; t++) {
        const int nxt = (cur == 2) ? 0 : cur + 1;
        gemm_stage(Ap, Wp, As3, Bs3, nxt, t + 1, gm, gn, lin);
        VMW(4);            // retire tile t's 4 loads; t+1 stays in flight
        BAR();             // single barrier: publishes tile t, bounds skew
        gemm_step(As3 + cur * 8192, Bs3 + cur * 8192, wr, wc, r, g, acc);
        cur = nxt;
    }
    VMW(0);
    BAR();
    gemm_step(As3 + cur * 8192, Bs3 + cur * 8192, wr, wc, r, g, acc);

    // epilogue: C/D map reg i -> row 4g+i, col r (verified rounds 1-17)
#pragma unroll
    for (int m = 0; m < 4; m++) {
        const int orow = gm + wr * 64 + m * 16 + g * 4;
#pragma unroll
        for (int n = 0; n < 4; n++) {
            const int ocol = gn + wc * 64 + n * 16 + r;
            const float bv = bias[ocol];
#pragma unroll
            for (int i = 0; i < 4; i++) {
                const float vout = (acc[m][n][i] + bv) * scale;
                const int row = orow + i;
                if (mode == 0) {
                    const int b = row >> 11, s = row & 2047;
                    const int h = ocol >> 6, hd = ocol & 63;
                    ((short*)Out)[(((size_t)(b * NH + h) * NS + s) << 6) + hd] = f2bf(vout);
                } else if (mode == 1) {
                    const int b = row >> 11, s = row & 2047;
                    const int h = ocol >> 6, hd = ocol & 63;
                    ((short*)Out)[((size_t)(b * NH + h) * HD + hd) * NS + s] = f2bf(vout);
                } else {
                    ((float*)Out)[(size_t)row * ND + ocol] = vout;
                }
            }
        }
    }
}

// grid (32,8,3) flattened + XCD-chunked swizzle: fid%8 -> XCD; each XCD gets
// 96 consecutive swz = 3 complete (z,gn) B-panel groups (768%8==0, bijective).
__global__ __launch_bounds__(256, 3) void gemm_qkv(const short* __restrict__ Qin,
                                                   const short* __restrict__ Kin,
                                                   const short* __restrict__ Vin,
                                                   const short* __restrict__ WtAll,
                                                   const float* __restrict__ bq,
                                                   const float* __restrict__ bk,
                                                   const float* __restrict__ bv,
                                                   short* __restrict__ Qo,
                                                   short* __restrict__ Ko,
                                                   short* __restrict__ Vto) {
    __shared__ __align__(16) char As[3 * 8192];
    __shared__ __align__(16) char Bs[3 * 8192];
    const int fid = blockIdx.x + 32 * (blockIdx.y + 8 * blockIdx.z);  // 0..767
    const int swz = (fid & 7) * 96 + (fid >> 3);
    const int gm = (swz & 31) * 128;
    const int rest = swz >> 5;          // 0..23
    const int gn = (rest & 7) * 128;
    const int z = rest >> 3;
    const short* A = (z == 0) ? Qin : (z == 1) ? Kin : Vin;
    const short* Wt = WtAll + (size_t)z * ND * ND;
    const float* bias = (z == 0) ? bq : (z == 1) ? bk : bv;
    void* Out = (z == 0) ? (void*)Qo : (z == 1) ? (void*)Ko : (void*)Vto;
    const float scale = (z == 0) ? QSCALE : 1.0f;
    const int mode = (z == 2) ? 1 : 0;
    gemm_body(A, Wt, bias, Out, mode, scale, gm, gn, As, Bs);
}

// grid (32,8): each XCD gets 32 consecutive swz = one full gn panel.
__global__ __launch_bounds__(256, 3) void gemm_fin(const short* __restrict__ Ctx,
                                                   const short* __restrict__ WtAll,
                                                   const float* __restrict__ bo,
                                                   float* __restrict__ Out) {
    __shared__ __align__(16) char As[3 * 8192];
    __shared__ __align__(16) char Bs[3 * 8192];
    const int fid = blockIdx.x + 32 * blockIdx.y;   // 0..255
    const int swz = (fid & 7) * 32 + (fid >> 3);
    const int gm = (swz & 31) * 128;
    const int gn = (swz >> 5) * 128;
    gemm_body(Ctx, WtAll + (size_t)3 * ND * ND, bo, Out, 2, 1.0f, gm, gn, As, Bs);
}

// ---------------------------------------------------------------------------
// Attention v7s (round-17 verified): 3-deep K/V ring, ONE barrier per tile.
// 256 blocks x 512 threads; wave = 64 q rows x 1024 keys; LDS-staged K/V;
// counted vmcnt; un-normalized single-pass softmax via exp2 (Q pre-scaled);
// P->PV A-frag via cvt_pk + permlane32_swap; merge of 2 key-halves via LDS.
// ---------------------------------------------------------------------------
static __device__ __forceinline__ void stage2(const char* Kp8, const char* Vp8,
                                              char* Kbuf, char* Vbuf,
                                              int t, int w, int l) {
#pragma unroll
    for (int jj = 0; jj < 2; jj++) {
        const int chunk = w * 2 + jj;                   // 0..15
        const int half = chunk >> 3;                    // key half
        const int lin = ((chunk & 7) << 10) + l * 16;   // 0..8191 in subtile
        const int sw = lin ^ (((lin >> 7) & 7) << 4);
        const int row = sw >> 7, col = sw & 127;
        gload16(Kp8 + (size_t)(half * 1024 + t * 64 + row) * 128 + col,
                Kbuf + half * 8192 + ((chunk & 7) << 10));
        gload16(Vp8 + (size_t)row * (NS * 2) + (half * 1024 + t * 64) * 2 + col,
                Vbuf + half * 8192 + ((chunk & 7) << 10));
    }
}

__global__ __launch_bounds__(512, 2) void attn_kern(const short* __restrict__ Q,
                                                    const short* __restrict__ K,
                                                    const short* __restrict__ Vt,
                                                    short* __restrict__ Ctx) {
    __shared__ __align__(16) char smem[3][2][16384];   // staging ring [buf][K/V]
    __shared__ float rsbuf[8][2][32];                   // [wave][qc][qcol]

    const int tid = threadIdx.x;
    const int w = tid >> 6;        // 0..7
    const int l = tid & 63;
    const int c = l & 31;
    const int h = l >> 5;
    const int h16 = h << 4;

    const int bid = blockIdx.x;
    const int swb = (bid & 7) * 32 + (bid >> 3);
    const int bh = swb >> 3;
    const int qt = swb & 7;
    const int g = w & 3;           // q-group within block
    const int khalf = w >> 2;      // key half
    const int qw = qt * 256 + g * 64;

    const short* Qp = Q + (size_t)bh * NS * HD;
    const char* Kp8 = (const char*)(K + (size_t)bh * NS * HD);
    const char* Vp8 = (const char*)(Vt + (size_t)bh * HD * NS);

    bf16x8 qf[2][4];
#pragma unroll
    for (int qc = 0; qc < 2; qc++)
#pragma unroll
        for (int st = 0; st < 4; st++)
            qf[qc][st] = *(const bf16x8*)(Qp + (size_t)(qw + qc * 32 + c) * HD +
                                          st * 16 + h * 8);

    f32x16 acc[2][2];
#pragma unroll
    for (int qc = 0; qc < 2; qc++)
#pragma unroll
        for (int dt = 0; dt < 2; dt++) acc[qc][dt] = (f32x16)(0.f);
    float rs0 = 0.f, rs1 = 0.f;

    const int sx = (c & 7) << 4;

    stage2(Kp8, Vp8, smem[0][0], smem[0][1], 0, w, l);

    int bufi = 0;
#pragma unroll 1
    for (int t = 0; t < 16; t++) {
        int nxt = bufi;
        if (t < 15) {
            nxt = (bufi == 2) ? 0 : bufi + 1;
            stage2(Kp8, Vp8, smem[nxt][0], smem[nxt][1], t + 1, w, l);
            VMW(4);            // retire tile t's loads; t+1 stays in flight
        } else {
            VMW(0);
        }
        BAR();                 // single barrier per tile

        const char* Kt = smem[bufi][0] + khalf * 8192;
        const char* Vv = smem[bufi][1] + khalf * 8192;

#pragma unroll
        for (int ktile = 0; ktile < 2; ktile++) {
            bf16x8 kf[4];
#pragma unroll
            for (int st = 0; st < 4; st++)
                kf[st] = *(const bf16x8*)(Kt + ((ktile * 32 + c) << 7) +
                                          ((st * 32 + h16) ^ sx));
            f32x16 S0 = (f32x16)(0.f), S1 = (f32x16)(0.f);
#pragma unroll
            for (int st = 0; st < 4; st++) {
                S0 = __builtin_amdgcn_mfma_f32_32x32x16_bf16(kf[st], qf[0][st], S0, 0, 0, 0);
                S1 = __builtin_amdgcn_mfma_f32_32x32x16_bf16(kf[st], qf[1][st], S1, 0, 0, 0);
            }

            float tv0[16], tv1[16];
#pragma unroll
            for (int i = 0; i < 16; i++) {
                tv0[i] = EXP2(S0[i]); rs0 += tv0[i];
                tv1[i] = EXP2(S1[i]); rs1 += tv1[i];
            }
            unsigned p0a[4], p0b[4], p1a[4], p1b[4];
#pragma unroll
            for (int q4 = 0; q4 < 4; q4++) {
                p0a[q4] = cvtpk(tv0[4 * q4], tv0[4 * q4 + 1]);
                p0b[q4] = cvtpk(tv0[4 * q4 + 2], tv0[4 * q4 + 3]);
                p1a[q4] = cvtpk(tv1[4 * q4], tv1[4 * q4 + 1]);
                p1b[q4] = cvtpk(tv1[4 * q4 + 2], tv1[4 * q4 + 3]);
            }

#pragma unroll
            for (int ks = 0; ks < 2; ks++) {
                unsigned a0 = p0a[2 * ks], b0 = p0a[2 * ks + 1];
                unsigned a1 = p0b[2 * ks], b1 = p0b[2 * ks + 1];
                plswap(a0, b0); plswap(a1, b1);
                u32x4 pw0; pw0[0] = a0; pw0[1] = a1; pw0[2] = b0; pw0[3] = b1;
                bf16x8 pa0 = __builtin_bit_cast(bf16x8, pw0);
                unsigned c0 = p1a[2 * ks], d0 = p1a[2 * ks + 1];
                unsigned c1 = p1b[2 * ks], d1 = p1b[2 * ks + 1];
                plswap(c0, d0); plswap(c1, d1);
                u32x4 pw1; pw1[0] = c0; pw1[1] = c1; pw1[2] = d0; pw1[3] = d1;
                bf16x8 pa1 = __builtin_bit_cast(bf16x8, pw1);
#pragma unroll
                for (int dt = 0; dt < 2; dt++) {
                    bf16x8 vb = *(const bf16x8*)(Vv + ((dt * 32 + c) << 7) +
                                                 ((ktile * 64 + ks * 32 + h16) ^ sx));
                    acc[0][dt] = __builtin_amdgcn_mfma_f32_32x32x16_bf16(pa0, vb, acc[0][dt], 0, 0, 0);
                    acc[1][dt] = __builtin_amdgcn_mfma_f32_32x32x16_bf16(pa1, vb, acc[1][dt], 0, 0, 0);
                }
            }
        }
        bufi = nxt;
    }

    rs0 += __shfl_xor(rs0, 32);
    rs1 += __shfl_xor(rs1, 32);

    __syncthreads();   // all waves done with smem ring before merge reuse
    if (h == 0) { rsbuf[w][0][c] = rs0; rsbuf[w][1][c] = rs1; }

    float* sumbuf = (float*)&smem[0][0][0];   // 64KB: [g][64 q][64 d]
    if (w >= 4) {
#pragma unroll
        for (int qc = 0; qc < 2; qc++)
#pragma unroll
            for (int q4 = 0; q4 < 4; q4++)
#pragma unroll
                for (int i = 0; i < 4; i++) {
                    const int qrow = qc * 32 + i + 8 * q4 + 4 * h;
#pragma unroll
                    for (int dt = 0; dt < 2; dt++)
                        sumbuf[((g * 64 + qrow) << 6) + dt * 32 + c] =
                            acc[qc][dt][q4 * 4 + i];
                }
    }
    __syncthreads();
    if (w < 4) {
        const int b = bh >> 4, hh = bh & 15;
#pragma unroll
        for (int qc = 0; qc < 2; qc++)
#pragma unroll
            for (int q4 = 0; q4 < 4; q4++)
#pragma unroll
                for (int i = 0; i < 4; i++) {
                    const int qrow32 = i + 8 * q4 + 4 * h;
                    const int qrow = qc * 32 + qrow32;
                    const float inv = 1.0f / (rsbuf[g][qc][qrow32] +
                                              rsbuf[4 + g][qc][qrow32]);
                    short* op = Ctx + ((size_t)b * NS + qt * 256 + g * 64 + qrow) * ND +
                                hh * HD;
#pragma unroll
                    for (int dt = 0; dt < 2; dt++) {
                        const float val = acc[qc][dt][q4 * 4 + i] +
                                          sumbuf[((g * 64 + qrow) << 6) + dt * 32 + c];
                        op[dt * 32 + c] = f2bf(val * inv);
                    }
                }
    }
}

// ---------------------------------------------------------------------------
extern "C" void kernel_launch(void* const* d_in, const int* in_sizes, int n_in,
                              void* d_out, int out_size, void* d_ws, size_t ws_size,
                              hipStream_t stream) {
    (void)in_sizes; (void)n_in; (void)out_size; (void)ws_size;
    const float* query = (const float*)d_in[0];
    const float* key_  = (const float*)d_in[1];
    const float* value = (const float*)d_in[2];
    const float* Wq = (const float*)d_in[3];
    const float* bq = (const float*)d_in[4];
    const float* Wk = (const float*)d_in[5];
    const float* bk = (const float*)d_in[6];
    const float* Wv = (const float*)d_in[7];
    const float* bv = (const float*)d_in[8];
    const float* Wo = (const float*)d_in[9];
    const float* bo = (const float*)d_in[10];

    char* ws = (char*)d_ws;
    const size_t MB = 1024 * 1024;
    short* WtAll = (short*)ws;                 // 8 MB: 4x [1024][1024] bf16
    short* Qin = (short*)(ws + 8 * MB);
    short* Kin = (short*)(ws + 16 * MB);
    short* Vin = (short*)(ws + 24 * MB);
    short* Qb  = (short*)(ws + 32 * MB);
    short* Kb  = (short*)(ws + 40 * MB);
    short* Vtb = (short*)(ws + 48 * MB);
    short* Ctx = (short*)(ws + 8 * MB);        // reuse Qin after gemm_qkv

    prep_all<<<dim3(2048, 1, 4), 256, 0, stream>>>(query, key_, value,
                                                   Wq, Wk, Wv, Wo,
                                                   Qin, Kin, Vin, WtAll);
    gemm_qkv<<<dim3(32, 8, 3), 256, 0, stream>>>(Qin, Kin, Vin, WtAll,
                                                 bq, bk, bv, Qb, Kb, Vtb);
    attn_kern<<<dim3(256), 512, 0, stream>>>(Qb, Kb, Vtb, Ctx);
    gemm_fin<<<dim3(32, 8), 256, 0, stream>>>(Ctx, WtAll, bo, (float*)d_out);
}

// Round 19
// 111.212 us; speedup vs baseline: 1.1210x; 1.1210x over previous
//
#include <hip/hip_runtime.h>
#include <hip/hip_bf16.h>
#include <stdint.h>

// B=2, S=2048, D=1024, H=16, HD=64.
// KL bias = per-row constant -> softmax-invariant -> dropped.
// out = softmax(QK^T/8) V with 4 dense projections. bf16 MFMA, fp32 accum.
// Q pre-scaled by log2(e)/8 so softmax is exp2().
// Round 19: restore round-17 verbatim (verified best, 111.4us):
// fused prep_all; single-barrier 3-ring counted-vmcnt GEMMs; attn v7s
// (3-deep K/V ring, one barrier per tile). Round-18's XCD swizzle reverted
// (it raised FETCH 37->44MB and cost 10us: A-stream locality dominates).

#define NB 2
#define NS 2048
#define ND 1024
#define NH 16
#define HD 64

typedef short bf16x8 __attribute__((ext_vector_type(8)));
typedef short bf16x4 __attribute__((ext_vector_type(4)));
typedef float f32x4 __attribute__((ext_vector_type(4)));
typedef float f32x16 __attribute__((ext_vector_type(16)));
typedef unsigned int u32x4 __attribute__((ext_vector_type(4)));

static __device__ __forceinline__ short f2bf(float f) {
    uint32_t u = __builtin_bit_cast(uint32_t, f);
    uint32_t r = (u + 0x7fffu + ((u >> 16) & 1u)) >> 16;
    return (short)(uint16_t)r;
}

static __device__ __forceinline__ unsigned int cvtpk(float lo, float hi) {
    unsigned int r;
    asm("v_cvt_pk_bf16_f32 %0, %1, %2" : "=v"(r) : "v"(lo), "v"(hi));
    return r;
}

#if __has_builtin(__builtin_amdgcn_exp2f)
#define EXP2(x) __builtin_amdgcn_exp2f(x)
#else
#define EXP2(x) exp2f(x)
#endif

static __device__ __forceinline__ void plswap(unsigned& a, unsigned& b) {
#if __has_builtin(__builtin_amdgcn_permlane32_swap)
    auto r = __builtin_amdgcn_permlane32_swap(a, b, false, false);
    a = r[0]; b = r[1];
#else
    const int l = (int)(threadIdx.x & 63);
    unsigned bl = __shfl(b, l & 31);
    unsigned ah = __shfl(a, (l & 31) + 32);
    a = (l < 32) ? a : bl;
    b = (l < 32) ? ah : b;
#endif
}

typedef __attribute__((address_space(1))) const unsigned int glob_u32;
typedef __attribute__((address_space(3))) unsigned int lds_u32;
static __device__ __forceinline__ void gload16(const void* g, void* l) {
    __builtin_amdgcn_global_load_lds((glob_u32*)g, (lds_u32*)l, 16, 0, 0);
}

#define VMW(N) do { asm volatile("s_waitcnt vmcnt(" #N ")" ::: "memory"); \
                    __builtin_amdgcn_sched_barrier(0); } while (0)
#define BAR()  do { __builtin_amdgcn_s_barrier();                          \
                    __builtin_amdgcn_sched_barrier(0); } while (0)
#define SFENCE() __builtin_amdgcn_sched_barrier(0)

// ---------------------------------------------------------------------------
// prep_all: z=0..2 -> fp32->bf16 cast of query/key/value (2048 blocks each);
//           z=3    -> Wt[n][k] = bf16(W[k][n]) for 4 weights (2 tiles/block).
// ---------------------------------------------------------------------------
__global__ __launch_bounds__(256) void prep_all(const float* __restrict__ q,
                                                const float* __restrict__ k,
                                                const float* __restrict__ v,
                                                const float* __restrict__ W0,
                                                const float* __restrict__ W1,
                                                const float* __restrict__ W2,
                                                const float* __restrict__ W3,
                                                short* __restrict__ Qo,
                                                short* __restrict__ Ko,
                                                short* __restrict__ Vo,
                                                short* __restrict__ WtAll) {
    __shared__ short tile[32][33];
    const int z = blockIdx.z;
    if (z < 3) {
        const float* src = (z == 0) ? q : (z == 1) ? k : v;
        short* dst = (z == 0) ? Qo : (z == 1) ? Ko : Vo;
        const size_t i = ((size_t)blockIdx.x * 256 + threadIdx.x) * 8;
        f32x4 a = *(const f32x4*)(src + i);
        f32x4 b = *(const f32x4*)(src + i + 4);
        bf16x8 o;
        o[0] = f2bf(a[0]); o[1] = f2bf(a[1]); o[2] = f2bf(a[2]); o[3] = f2bf(a[3]);
        o[4] = f2bf(b[0]); o[5] = f2bf(b[1]); o[6] = f2bf(b[2]); o[7] = f2bf(b[3]);
        *(bf16x8*)(dst + i) = o;
        return;
    }
    const int tx = threadIdx.x & 31;
    const int ty = threadIdx.x >> 5;
#pragma unroll 1
    for (int it = 0; it < 2; ++it) {
        const int tt = blockIdx.x * 2 + it;          // 0..4095
        const int which = tt >> 10;
        const float* W = (which == 0) ? W0 : (which == 1) ? W1
                       : (which == 2) ? W2 : W3;
        short* Wt = WtAll + (size_t)which * (ND * ND);
        const int t = tt & 1023;
        const int k0 = (t >> 5) * 32, n0 = (t & 31) * 32;
#pragma unroll
        for (int i = 0; i < 4; i++)
            tile[ty + i * 8][tx] = f2bf(W[(size_t)(k0 + ty + i * 8) * ND + n0 + tx]);
        __syncthreads();
#pragma unroll
        for (int i = 0; i < 4; i++)
            Wt[(size_t)(n0 + ty + i * 8) * ND + k0 + tx] = tile[tx][ty + i * 8];
        __syncthreads();
    }
}

#define QSCALE 0.18033688011112042f  // log2(e)/8

// ---------------------------------------------------------------------------
// GEMM body: 128x128 tile, BK=32, global_load_lds, 3-ring, depth-1 prefetch,
// counted vmcnt, ONE barrier per K-step (safe: 3 does not divide 1+1).
// Both-sides XOR swizzle f(row)=((row^row>>2)&3)<<4.
// ---------------------------------------------------------------------------
static __device__ __forceinline__ void gemm_stage(const char* A, const char* W,
                                                  char* As3, char* Bs3,
                                                  int buf, int tile,
                                                  int gm, int gn, int lin) {
#pragma unroll
    for (int j = 0; j < 2; j++) {
        const int lj = lin + (j << 10);
        const int row = lj >> 6;
        const int colL = (lj & 63) ^ (((row ^ (row >> 2)) & 3) << 4);
        gload16(A + (size_t)(gm + row) * (ND * 2) + tile * 64 + colL,
                As3 + buf * 8192 + lj);
        gload16(W + (size_t)(gn + row) * (ND * 2) + tile * 64 + colL,
                Bs3 + buf * 8192 + lj);
    }
    SFENCE();
}

static __device__ __forceinline__ void gemm_step(const char* AsB, const char* BsB,
                                                 int wr, int wc, int r, int g,
                                                 f32x4 (&acc)[4][4]) {
    bf16x8 af[4], bfv[4];
#pragma unroll
    for (int m = 0; m < 4; m++) {
        const int ar = wr * 64 + m * 16 + r;
        const int fa = ((ar ^ (ar >> 2)) & 3) << 4;
        af[m] = *(const bf16x8*)(AsB + ar * 64 + ((g << 4) ^ fa));
    }
#pragma unroll
    for (int n = 0; n < 4; n++) {
        const int br = wc * 64 + n * 16 + r;
        const int fb = ((br ^ (br >> 2)) & 3) << 4;
        bfv[n] = *(const bf16x8*)(BsB + br * 64 + ((g << 4) ^ fb));
    }
#pragma unroll
    for (int m = 0; m < 4; m++)
#pragma unroll
        for (int n = 0; n < 4; n++)
            acc[m][n] = __builtin_amdgcn_mfma_f32_16x16x32_bf16(
                af[m], bfv[n], acc[m][n], 0, 0, 0);
}

static __device__ __forceinline__ void gemm_body(const short* __restrict__ A,
                                                 const short* __restrict__ Wt,
                                                 const float* __restrict__ bias,
                                                 void* __restrict__ Out,
                                                 int mode, float scale,
                                                 char* As3, char* Bs3) {
    const int tid = threadIdx.x;
    const int gm = blockIdx.x * 128;
    const int gn = blockIdx.y * 128;
    const int w = tid >> 6;
    const int l = tid & 63;
    const int r = l & 15;
    const int g = l >> 4;
    const int wr = w >> 1, wc = w & 1;
    const char* Ap = (const char*)A;
    const char* Wp = (const char*)Wt;

    f32x4 acc[4][4];
#pragma unroll
    for (int m = 0; m < 4; m++)
#pragma unroll
        for (int n = 0; n < 4; n++) acc[m][n] = (f32x4){0.f, 0.f, 0.f, 0.f};

    const int lin = ((w * 2) << 10) + l * 16;

    // prologue: tile 0 -> buf 0
    gemm_stage(Ap, Wp, As3, Bs3, 0, 0, gm, gn, lin);

    int cur = 0;
#pragma unroll 1
    for (int t = 0; t < ND / 32 - 1; t++) {
        const int nxt = (cur == 2) ? 0 : cur + 1;
        gemm_stage(Ap, Wp, As3, Bs3, nxt, t + 1, gm, gn, lin);
        VMW(4);            // retire tile t's 4 loads; t+1 stays in flight
        BAR();             // single barrier: publishes tile t, bounds skew
        gemm_step(As3 + cur * 8192, Bs3 + cur * 8192, wr, wc, r, g, acc);
        cur = nxt;
    }
    VMW(0);
    BAR();
    gemm_step(As3 + cur * 8192, Bs3 + cur * 8192, wr, wc, r, g, acc);

    // epilogue: C/D map reg i -> row 4g+i, col r (verified rounds 1-17)
#pragma unroll
    for (int m = 0; m < 4; m++) {
        const int orow = gm + wr * 64 + m * 16 + g * 4;
#pragma unroll
        for (int n = 0; n < 4; n++) {
            const int ocol = gn + wc * 64 + n * 16 + r;
            const float bv = bias[ocol];
#pragma unroll
            for (int i = 0; i < 4; i++) {
                const float vout = (acc[m][n][i] + bv) * scale;
                const int row = orow + i;
                if (mode == 0) {
                    const int b = row >> 11, s = row & 2047;
                    const int h = ocol >> 6, hd = ocol & 63;
                    ((short*)Out)[(((size_t)(b * NH + h) * NS + s) << 6) + hd] = f2bf(vout);
                } else if (mode == 1) {
                    const int b = row >> 11, s = row & 2047;
                    const int h = ocol >> 6, hd = ocol & 63;
                    ((short*)Out)[((size_t)(b * NH + h) * HD + hd) * NS + s] = f2bf(vout);
                } else {
                    ((float*)Out)[(size_t)row * ND + ocol] = vout;
                }
            }
        }
    }
}

__global__ __launch_bounds__(256, 3) void gemm_qkv(const short* __restrict__ Qin,
                                                   const short* __restrict__ Kin,
                                                   const short* __restrict__ Vin,
                                                   const short* __restrict__ WtAll,
                                                   const float* __restrict__ bq,
                                                   const float* __restrict__ bk,
                                                   const float* __restrict__ bv,
                                                   short* __restrict__ Qo,
                                                   short* __restrict__ Ko,
                                                   short* __restrict__ Vto) {
    __shared__ __align__(16) char As[3 * 8192];
    __shared__ __align__(16) char Bs[3 * 8192];
    const int z = blockIdx.z;
    const short* A = (z == 0) ? Qin : (z == 1) ? Kin : Vin;
    const short* Wt = WtAll + (size_t)z * ND * ND;
    const float* bias = (z == 0) ? bq : (z == 1) ? bk : bv;
    void* Out = (z == 0) ? (void*)Qo : (z == 1) ? (void*)Ko : (void*)Vto;
    const float scale = (z == 0) ? QSCALE : 1.0f;
    const int mode = (z == 2) ? 1 : 0;
    gemm_body(A, Wt, bias, Out, mode, scale, As, Bs);
}

__global__ __launch_bounds__(256, 3) void gemm_fin(const short* __restrict__ Ctx,
                                                   const short* __restrict__ WtAll,
                                                   const float* __restrict__ bo,
                                                   float* __restrict__ Out) {
    __shared__ __align__(16) char As[3 * 8192];
    __shared__ __align__(16) char Bs[3 * 8192];
    gemm_body(Ctx, WtAll + (size_t)3 * ND * ND, bo, Out, 2, 1.0f, As, Bs);
}

// ---------------------------------------------------------------------------
// Attention v7s (round-17 verified): 3-deep K/V ring, ONE barrier per tile.
// 256 blocks x 512 threads; wave = 64 q rows x 1024 keys; LDS-staged K/V;
// counted vmcnt; un-normalized single-pass softmax via exp2 (Q pre-scaled);
// P->PV A-frag via cvt_pk + permlane32_swap; merge of 2 key-halves via LDS.
// ---------------------------------------------------------------------------
static __device__ __forceinline__ void stage2(const char* Kp8, const char* Vp8,
                                              char* Kbuf, char* Vbuf,
                                              int t, int w, int l) {
#pragma unroll
    for (int jj = 0; jj < 2; jj++) {
        const int chunk = w * 2 + jj;                   // 0..15
        const int half = chunk >> 3;                    // key half
        const int lin = ((chunk & 7) << 10) + l * 16;   // 0..8191 in subtile
        const int sw = lin ^ (((lin >> 7) & 7) << 4);
        const int row = sw >> 7, col = sw & 127;
        gload16(Kp8 + (size_t)(half * 1024 + t * 64 + row) * 128 + col,
                Kbuf + half * 8192 + ((chunk & 7) << 10));
        gload16(Vp8 + (size_t)row * (NS * 2) + (half * 1024 + t * 64) * 2 + col,
                Vbuf + half * 8192 + ((chunk & 7) << 10));
    }
}

__global__ __launch_bounds__(512, 2) void attn_kern(const short* __restrict__ Q,
                                                    const short* __restrict__ K,
                                                    const short* __restrict__ Vt,
                                                    short* __restrict__ Ctx) {
    __shared__ __align__(16) char smem[3][2][16384];   // staging ring [buf][K/V]
    __shared__ float rsbuf[8][2][32];                   // [wave][qc][qcol]

    const int tid = threadIdx.x;
    const int w = tid >> 6;        // 0..7
    const int l = tid & 63;
    const int c = l & 31;
    const int h = l >> 5;
    const int h16 = h << 4;

    const int bid = blockIdx.x;
    const int swb = (bid & 7) * 32 + (bid >> 3);
    const int bh = swb >> 3;
    const int qt = swb & 7;
    const int g = w & 3;           // q-group within block
    const int khalf = w >> 2;      // key half
    const int qw = qt * 256 + g * 64;

    const short* Qp = Q + (size_t)bh * NS * HD;
    const char* Kp8 = (const char*)(K + (size_t)bh * NS * HD);
    const char* Vp8 = (const char*)(Vt + (size_t)bh * HD * NS);

    bf16x8 qf[2][4];
#pragma unroll
    for (int qc = 0; qc < 2; qc++)
#pragma unroll
        for (int st = 0; st < 4; st++)
            qf[qc][st] = *(const bf16x8*)(Qp + (size_t)(qw + qc * 32 + c) * HD +
                                          st * 16 + h * 8);

    f32x16 acc[2][2];
#pragma unroll
    for (int qc = 0; qc < 2; qc++)
#pragma unroll
        for (int dt = 0; dt < 2; dt++) acc[qc][dt] = (f32x16)(0.f);
    float rs0 = 0.f, rs1 = 0.f;

    const int sx = (c & 7) << 4;

    stage2(Kp8, Vp8, smem[0][0], smem[0][1], 0, w, l);

    int bufi = 0;
#pragma unroll 1
    for (int t = 0; t < 16; t++) {
        int nxt = bufi;
        if (t < 15) {
            nxt = (bufi == 2) ? 0 : bufi + 1;
            stage2(Kp8, Vp8, smem[nxt][0], smem[nxt][1], t + 1, w, l);
            VMW(4);            // retire tile t's loads; t+1 stays in flight
        } else {
            VMW(0);
        }
        BAR();                 // single barrier per tile

        const char* Kt = smem[bufi][0] + khalf * 8192;
        const char* Vv = smem[bufi][1] + khalf * 8192;

#pragma unroll
        for (int ktile = 0; ktile < 2; ktile++) {
            bf16x8 kf[4];
#pragma unroll
            for (int st = 0; st < 4; st++)
                kf[st] = *(const bf16x8*)(Kt + ((ktile * 32 + c) << 7) +
                                          ((st * 32 + h16) ^ sx));
            f32x16 S0 = (f32x16)(0.f), S1 = (f32x16)(0.f);
#pragma unroll
            for (int st = 0; st < 4; st++) {
                S0 = __builtin_amdgcn_mfma_f32_32x32x16_bf16(kf[st], qf[0][st], S0, 0, 0, 0);
                S1 = __builtin_amdgcn_mfma_f32_32x32x16_bf16(kf[st], qf[1][st], S1, 0, 0, 0);
            }

            float tv0[16], tv1[16];
#pragma unroll
            for (int i = 0; i < 16; i++) {
                tv0[i] = EXP2(S0[i]); rs0 += tv0[i];
                tv1[i] = EXP2(S1[i]); rs1 += tv1[i];
            }
            unsigned p0a[4], p0b[4], p1a[4], p1b[4];
#pragma unroll
            for (int q4 = 0; q4 < 4; q4++) {
                p0a[q4] = cvtpk(tv0[4 * q4], tv0[4 * q4 + 1]);
                p0b[q4] = cvtpk(tv0[4 * q4 + 2], tv0[4 * q4 + 3]);
                p1a[q4] = cvtpk(tv1[4 * q4], tv1[4 * q4 + 1]);
                p1b[q4] = cvtpk(tv1[4 * q4 + 2], tv1[4 * q4 + 3]);
            }

#pragma unroll
            for (int ks = 0; ks < 2; ks++) {
                unsigned a0 = p0a[2 * ks], b0 = p0a[2 * ks + 1];
                unsigned a1 = p0b[2 * ks], b1 = p0b[2 * ks + 1];
                plswap(a0, b0); plswap(a1, b1);
                u32x4 pw0; pw0[0] = a0; pw0[1] = a1; pw0[2] = b0; pw0[3] = b1;
                bf16x8 pa0 = __builtin_bit_cast(bf16x8, pw0);
                unsigned c0 = p1a[2 * ks], d0 = p1a[2 * ks + 1];
                unsigned c1 = p1b[2 * ks], d1 = p1b[2 * ks + 1];
                plswap(c0, d0); plswap(c1, d1);
                u32x4 pw1; pw1[0] = c0; pw1[1] = c1; pw1[2] = d0; pw1[3] = d1;
                bf16x8 pa1 = __builtin_bit_cast(bf16x8, pw1);
#pragma unroll
                for (int dt = 0; dt < 2; dt++) {
                    bf16x8 vb = *(const bf16x8*)(Vv + ((dt * 32 + c) << 7) +
                                                 ((ktile * 64 + ks * 32 + h16) ^ sx));
                    acc[0][dt] = __builtin_amdgcn_mfma_f32_32x32x16_bf16(pa0, vb, acc[0][dt], 0, 0, 0);
                    acc[1][dt] = __builtin_amdgcn_mfma_f32_32x32x16_bf16(pa1, vb, acc[1][dt], 0, 0, 0);
                }
            }
        }
        bufi = nxt;
    }

    rs0 += __shfl_xor(rs0, 32);
    rs1 += __shfl_xor(rs1, 32);

    __syncthreads();   // all waves done with smem ring before merge reuse
    if (h == 0) { rsbuf[w][0][c] = rs0; rsbuf[w][1][c] = rs1; }

    float* sumbuf = (float*)&smem[0][0][0];   // 64KB: [g][64 q][64 d]
    if (w >= 4) {
#pragma unroll
        for (int qc = 0; qc < 2; qc++)
#pragma unroll
            for (int q4 = 0; q4 < 4; q4++)
#pragma unroll
                for (int i = 0; i < 4; i++) {
                    const int qrow = qc * 32 + i + 8 * q4 + 4 * h;
#pragma unroll
                    for (int dt = 0; dt < 2; dt++)
                        sumbuf[((g * 64 + qrow) << 6) + dt * 32 + c] =
                            acc[qc][dt][q4 * 4 + i];
                }
    }
    __syncthreads();
    if (w < 4) {
        const int b = bh >> 4, hh = bh & 15;
#pragma unroll
        for (int qc = 0; qc < 2; qc++)
#pragma unroll
            for (int q4 = 0; q4 < 4; q4++)
#pragma unroll
                for (int i = 0; i < 4; i++) {
                    const int qrow32 = i + 8 * q4 + 4 * h;
                    const int qrow = qc * 32 + qrow32;
                    const float inv = 1.0f / (rsbuf[g][qc][qrow32] +
                                              rsbuf[4 + g][qc][qrow32]);
                    short* op = Ctx + ((size_t)b * NS + qt * 256 + g * 64 + qrow) * ND +
                                hh * HD;
#pragma unroll
                    for (int dt = 0; dt < 2; dt++) {
                        const float val = acc[qc][dt][q4 * 4 + i] +
                                          sumbuf[((g * 64 + qrow) << 6) + dt * 32 + c];
                        op[dt * 32 + c] = f2bf(val * inv);
                    }
                }
    }
}

// ---------------------------------------------------------------------------
extern "C" void kernel_launch(void* const* d_in, const int* in_sizes, int n_in,
                              void* d_out, int out_size, void* d_ws, size_t ws_size,
                              hipStream_t stream) {
    (void)in_sizes; (void)n_in; (void)out_size; (void)ws_size;
    const float* query = (const float*)d_in[0];
    const float* key_  = (const float*)d_in[1];
    const float* value = (const float*)d_in[2];
    const float* Wq = (const float*)d_in[3];
    const float* bq = (const float*)d_in[4];
    const float* Wk = (const float*)d_in[5];
    const float* bk = (const float*)d_in[6];
    const float* Wv = (const float*)d_in[7];
    const float* bv = (const float*)d_in[8];
    const float* Wo = (const float*)d_in[9];
    const float* bo = (const float*)d_in[10];

    char* ws = (char*)d_ws;
    const size_t MB = 1024 * 1024;
    short* WtAll = (short*)ws;                 // 8 MB: 4x [1024][1024] bf16
    short* Qin = (short*)(ws + 8 * MB);
    short* Kin = (short*)(ws + 16 * MB);
    short* Vin = (short*)(ws + 24 * MB);
    short* Qb  = (short*)(ws + 32 * MB);
    short* Kb  = (short*)(ws + 40 * MB);
    short* Vtb = (short*)(ws + 48 * MB);
    short* Ctx = (short*)(ws + 8 * MB);        // reuse Qin after gemm_qkv

    prep_all<<<dim3(2048, 1, 4), 256, 0, stream>>>(query, key_, value,
                                                   Wq, Wk, Wv, Wo,
                                                   Qin, Kin, Vin, WtAll);
    gemm_qkv<<<dim3(32, 8, 3), 256, 0, stream>>>(Qin, Kin, Vin, WtAll,
                                                 bq, bk, bv, Qb, Kb, Vtb);
    attn_kern<<<dim3(256), 512, 0, stream>>>(Qb, Kb, Vtb, Ctx);
    gemm_fin<<<dim3(32, 8), 256, 0, stream>>>(Ctx, WtAll, bo, (float*)d_out);
}